// Round 6
// baseline (770.506 us; speedup 1.0000x reference)
//
#include <hip/hip_runtime.h>
#include <math.h>

#define INPUT_DIM 128
#define OUT_DIM 128
#define NUM_GAUSS 20
#define NH 16
#define BM 64      // bonds per block in bond_proj
#define AST 150    // padded LDS row stride (8B-aligned float2 reads)
#define MAXT 16
#define WPB 4      // waves (segments) per block in attn_wave
#define SCALE 0.35355339059327373f

// W_key/W_value row layout: [0:128) h_bond(kj), [128:148) r_kj, [148:168) r_ji, [168:181) a_feat

static __device__ __forceinline__ void wave_lds_fence() {
    __asm__ volatile("s_waitcnt lgkmcnt(0)" ::: "memory");
    __builtin_amdgcn_wave_barrier();
}

__global__ __launch_bounds__(256) void rbf_kernel(
    const float* __restrict__ pos,
    const int*   __restrict__ bond_index,
    float* __restrict__ r_out,
    int E)
{
    int e = blockIdx.x * 256 + threadIdx.x;
    if (e >= E) return;
    int jrow = bond_index[e];
    int icol = bond_index[E + e];
    float dx = pos[icol*3+0] - pos[jrow*3+0];
    float dy = pos[icol*3+1] - pos[jrow*3+1];
    float dz = pos[icol*3+2] - pos[jrow*3+2];
    float dist = sqrtf(dx*dx + dy*dy + dz*dz);
    const float step = 10.f / (NUM_GAUSS - 1);
    const float coeff = -0.5f / (step * step);
    float v[NUM_GAUSS];
    #pragma unroll
    for (int g = 0; g < NUM_GAUSS; ++g) {
        float t = dist - g * step;
        v[g] = __expf(coeff * t * t);
    }
    float4* o = (float4*)&r_out[(size_t)e * NUM_GAUSS];
    #pragma unroll
    for (int q = 0; q < 5; ++q)
        o[q] = make_float4(v[4*q], v[4*q+1], v[4*q+2], v[4*q+3]);
}

// Register-tiled GEMM, phased to keep <=64 live accumulators:
//  phase1: KB,VB (K=148)   phase2: QE (K=128 + K=20, tanh)
//  phase3a: EA1, ERV=EA1*RV2 (K=20)   phase3b: RK2 -> QRK2[e][16] reduce
__global__ __launch_bounds__(256, 4) void bond_proj_kernel(
    const float* __restrict__ h_bond,
    const float* __restrict__ r_feat,
    const float* __restrict__ Wk,
    const float* __restrict__ Wv,
    const float* __restrict__ Wq,
    const float* __restrict__ We0,
    const float* __restrict__ We1,
    float* __restrict__ KB,
    float* __restrict__ VB,
    float* __restrict__ QE,
    float* __restrict__ EA1,
    float* __restrict__ ERV,
    float* __restrict__ QRK2,
    int E)
{
    __shared__ float As[BM * AST];
    const int tid = threadIdx.x;
    const int e0 = blockIdx.x * BM;

    // stage h (64x128) + r (64x20) into LDS (row stride AST=150)
    for (int i = tid; i < BM * 32; i += 256) {
        int e = i >> 5, c = (i & 31) << 2;
        float4 v = make_float4(0.f, 0.f, 0.f, 0.f);
        if (e0 + e < E) v = *(const float4*)&h_bond[(size_t)(e0 + e) * INPUT_DIM + c];
        float* dst = &As[e * AST + c];
        dst[0] = v.x; dst[1] = v.y; dst[2] = v.z; dst[3] = v.w;
    }
    for (int i = tid; i < BM * 5; i += 256) {
        int e = i / 5, q = (i % 5) << 2;
        float4 v = make_float4(0.f, 0.f, 0.f, 0.f);
        if (e0 + e < E) v = *(const float4*)&r_feat[(size_t)(e0 + e) * NUM_GAUSS + q];
        float* dst = &As[e * AST + 128 + q];
        dst[0] = v.x; dst[1] = v.y; dst[2] = v.z; dst[3] = v.w;
    }
    __syncthreads();

    const int em = tid >> 5;          // bond group: bonds em*8 .. em*8+7
    const int dn = (tid & 31) << 2;   // dim group: dims dn .. dn+3
    const float* AsB = &As[em * 8 * AST];

    // ---- phase 1: K and V (K = 148) ----
    {
        float aK[8][4], aV[8][4];
        #pragma unroll
        for (int m = 0; m < 8; ++m)
            #pragma unroll
            for (int j = 0; j < 4; ++j) { aK[m][j]=0.f; aV[m][j]=0.f; }

        for (int c = 0; c < 148; c += 2) {
            float4 wk0 = *(const float4*)&Wk[(c    ) * OUT_DIM + dn];
            float4 wk1 = *(const float4*)&Wk[(c + 1) * OUT_DIM + dn];
            float4 wv0 = *(const float4*)&Wv[(c    ) * OUT_DIM + dn];
            float4 wv1 = *(const float4*)&Wv[(c + 1) * OUT_DIM + dn];
            #pragma unroll
            for (int m = 0; m < 8; ++m) {
                float2 a = *(const float2*)&AsB[m * AST + c];   // broadcast b64
                aK[m][0] = fmaf(a.x, wk0.x, aK[m][0]); aK[m][1] = fmaf(a.x, wk0.y, aK[m][1]);
                aK[m][2] = fmaf(a.x, wk0.z, aK[m][2]); aK[m][3] = fmaf(a.x, wk0.w, aK[m][3]);
                aK[m][0] = fmaf(a.y, wk1.x, aK[m][0]); aK[m][1] = fmaf(a.y, wk1.y, aK[m][1]);
                aK[m][2] = fmaf(a.y, wk1.z, aK[m][2]); aK[m][3] = fmaf(a.y, wk1.w, aK[m][3]);
                aV[m][0] = fmaf(a.x, wv0.x, aV[m][0]); aV[m][1] = fmaf(a.x, wv0.y, aV[m][1]);
                aV[m][2] = fmaf(a.x, wv0.z, aV[m][2]); aV[m][3] = fmaf(a.x, wv0.w, aV[m][3]);
                aV[m][0] = fmaf(a.y, wv1.x, aV[m][0]); aV[m][1] = fmaf(a.y, wv1.y, aV[m][1]);
                aV[m][2] = fmaf(a.y, wv1.z, aV[m][2]); aV[m][3] = fmaf(a.y, wv1.w, aV[m][3]);
            }
        }
        #pragma unroll
        for (int m = 0; m < 8; ++m) {
            int e = e0 + em * 8 + m;
            if (e < E) {
                *(float4*)&KB[(size_t)e * OUT_DIM + dn] =
                    make_float4(aK[m][0], aK[m][1], aK[m][2], aK[m][3]);
                *(float4*)&VB[(size_t)e * OUT_DIM + dn] =
                    make_float4(aV[m][0], aV[m][1], aV[m][2], aV[m][3]);
            }
        }
    }

    // ---- phase 2: QE = (h@Wq) * tanh(r@We0) ----
    float qev[8][4];
    {
        float aQ[8][4], aE[8][4];
        #pragma unroll
        for (int m = 0; m < 8; ++m)
            #pragma unroll
            for (int j = 0; j < 4; ++j) { aQ[m][j]=0.f; aE[m][j]=0.f; }

        for (int c = 0; c < 128; c += 2) {
            float4 wq0 = *(const float4*)&Wq[(c    ) * OUT_DIM + dn];
            float4 wq1 = *(const float4*)&Wq[(c + 1) * OUT_DIM + dn];
            #pragma unroll
            for (int m = 0; m < 8; ++m) {
                float2 a = *(const float2*)&AsB[m * AST + c];
                aQ[m][0] = fmaf(a.x, wq0.x, aQ[m][0]); aQ[m][1] = fmaf(a.x, wq0.y, aQ[m][1]);
                aQ[m][2] = fmaf(a.x, wq0.z, aQ[m][2]); aQ[m][3] = fmaf(a.x, wq0.w, aQ[m][3]);
                aQ[m][0] = fmaf(a.y, wq1.x, aQ[m][0]); aQ[m][1] = fmaf(a.y, wq1.y, aQ[m][1]);
                aQ[m][2] = fmaf(a.y, wq1.z, aQ[m][2]); aQ[m][3] = fmaf(a.y, wq1.w, aQ[m][3]);
            }
        }
        for (int g = 0; g < 20; g += 2) {
            float4 w00 = *(const float4*)&We0[(g    ) * OUT_DIM + dn];
            float4 w01 = *(const float4*)&We0[(g + 1) * OUT_DIM + dn];
            #pragma unroll
            for (int m = 0; m < 8; ++m) {
                float2 a = *(const float2*)&AsB[m * AST + 128 + g];
                aE[m][0] = fmaf(a.x, w00.x, aE[m][0]); aE[m][1] = fmaf(a.x, w00.y, aE[m][1]);
                aE[m][2] = fmaf(a.x, w00.z, aE[m][2]); aE[m][3] = fmaf(a.x, w00.w, aE[m][3]);
                aE[m][0] = fmaf(a.y, w01.x, aE[m][0]); aE[m][1] = fmaf(a.y, w01.y, aE[m][1]);
                aE[m][2] = fmaf(a.y, w01.z, aE[m][2]); aE[m][3] = fmaf(a.y, w01.w, aE[m][3]);
            }
        }
        #pragma unroll
        for (int m = 0; m < 8; ++m) {
            #pragma unroll
            for (int j = 0; j < 4; ++j) qev[m][j] = aQ[m][j] * tanhf(aE[m][j]);
            int e = e0 + em * 8 + m;
            if (e < E)
                *(float4*)&QE[(size_t)e * OUT_DIM + dn] =
                    make_float4(qev[m][0], qev[m][1], qev[m][2], qev[m][3]);
        }
    }

    // ---- phase 3a: EA1 = tanh(r@We1), ERV = EA1 * (r@Wv[148:168]) ----
    {
        float a1[8][4], aS[8][4];
        #pragma unroll
        for (int m = 0; m < 8; ++m)
            #pragma unroll
            for (int j = 0; j < 4; ++j) { a1[m][j]=0.f; aS[m][j]=0.f; }

        for (int g = 0; g < 20; g += 2) {
            float4 w10 = *(const float4*)&We1[(g    ) * OUT_DIM + dn];
            float4 w11 = *(const float4*)&We1[(g + 1) * OUT_DIM + dn];
            float4 wv0 = *(const float4*)&Wv[(148 + g    ) * OUT_DIM + dn];
            float4 wv1 = *(const float4*)&Wv[(148 + g + 1) * OUT_DIM + dn];
            #pragma unroll
            for (int m = 0; m < 8; ++m) {
                float2 a = *(const float2*)&AsB[m * AST + 128 + g];
                a1[m][0] = fmaf(a.x, w10.x, a1[m][0]); a1[m][1] = fmaf(a.x, w10.y, a1[m][1]);
                a1[m][2] = fmaf(a.x, w10.z, a1[m][2]); a1[m][3] = fmaf(a.x, w10.w, a1[m][3]);
                a1[m][0] = fmaf(a.y, w11.x, a1[m][0]); a1[m][1] = fmaf(a.y, w11.y, a1[m][1]);
                a1[m][2] = fmaf(a.y, w11.z, a1[m][2]); a1[m][3] = fmaf(a.y, w11.w, a1[m][3]);
                aS[m][0] = fmaf(a.x, wv0.x, aS[m][0]); aS[m][1] = fmaf(a.x, wv0.y, aS[m][1]);
                aS[m][2] = fmaf(a.x, wv0.z, aS[m][2]); aS[m][3] = fmaf(a.x, wv0.w, aS[m][3]);
                aS[m][0] = fmaf(a.y, wv1.x, aS[m][0]); aS[m][1] = fmaf(a.y, wv1.y, aS[m][1]);
                aS[m][2] = fmaf(a.y, wv1.z, aS[m][2]); aS[m][3] = fmaf(a.y, wv1.w, aS[m][3]);
            }
        }
        #pragma unroll
        for (int m = 0; m < 8; ++m) {
            int e = e0 + em * 8 + m;
            if (e < E) {
                float t0 = tanhf(a1[m][0]), t1 = tanhf(a1[m][1]);
                float t2 = tanhf(a1[m][2]), t3 = tanhf(a1[m][3]);
                *(float4*)&EA1[(size_t)e * OUT_DIM + dn] = make_float4(t0, t1, t2, t3);
                *(float4*)&ERV[(size_t)e * OUT_DIM + dn] =
                    make_float4(t0 * aS[m][0], t1 * aS[m][1], t2 * aS[m][2], t3 * aS[m][3]);
            }
        }
    }

    // ---- phase 3b: RK2 = r@Wk[148:168] (regs only) -> QRK2[e][16] ----
    {
        float aR[8][4];
        #pragma unroll
        for (int m = 0; m < 8; ++m)
            #pragma unroll
            for (int j = 0; j < 4; ++j) aR[m][j] = 0.f;

        for (int g = 0; g < 20; g += 2) {
            float4 wk0 = *(const float4*)&Wk[(148 + g    ) * OUT_DIM + dn];
            float4 wk1 = *(const float4*)&Wk[(148 + g + 1) * OUT_DIM + dn];
            #pragma unroll
            for (int m = 0; m < 8; ++m) {
                float2 a = *(const float2*)&AsB[m * AST + 128 + g];
                aR[m][0] = fmaf(a.x, wk0.x, aR[m][0]); aR[m][1] = fmaf(a.x, wk0.y, aR[m][1]);
                aR[m][2] = fmaf(a.x, wk0.z, aR[m][2]); aR[m][3] = fmaf(a.x, wk0.w, aR[m][3]);
                aR[m][0] = fmaf(a.y, wk1.x, aR[m][0]); aR[m][1] = fmaf(a.y, wk1.y, aR[m][1]);
                aR[m][2] = fmaf(a.y, wk1.z, aR[m][2]); aR[m][3] = fmaf(a.y, wk1.w, aR[m][3]);
            }
        }
        const int l = tid & 63;
        const int hh = (tid & 31) >> 1;   // head owning dims dn..dn+3 (with partner lane)
        #pragma unroll
        for (int m = 0; m < 8; ++m) {
            float s = qev[m][0]*aR[m][0] + qev[m][1]*aR[m][1]
                    + qev[m][2]*aR[m][2] + qev[m][3]*aR[m][3];
            s += __shfl_xor(s, 1);
            int e = e0 + em * 8 + m;
            if ((l & 1) == 0 && e < E) QRK2[(size_t)e * NH + hh] = s;
        }
    }
}

// One 64-lane wave per segment; lane l owns dims (2l, 2l+1); head h = l>>2.
__global__ __launch_bounds__(256, 2) void attn_wave_kernel(
    const float* __restrict__ pos,
    const int*   __restrict__ idx_i,
    const int*   __restrict__ idx_j,
    const int*   __restrict__ idx_k,
    const int*   __restrict__ idx_kj,
    const float* __restrict__ Wk,
    const float* __restrict__ Wv,
    const float* __restrict__ KB,
    const float* __restrict__ VB,
    const float* __restrict__ QE,
    const float* __restrict__ EA1,
    const float* __restrict__ ERV,
    const float* __restrict__ QRK2,
    float* __restrict__ out,
    int E)
{
    __shared__ float afL[WPB][12][13];
    __shared__ float alphaL[WPB][12][16];

    // bijective XCD-aware swizzle: contiguous block ranges per XCD (m204)
    unsigned bid = blockIdx.x, nwg = gridDim.x;
    unsigned qq = nwg >> 3, rr = nwg & 7, xc = bid & 7, rest = bid >> 3;
    unsigned swz = (xc < rr ? xc * (qq + 1) : rr * (qq + 1) + (xc - rr) * qq) + rest;

    const int l = threadIdx.x & 63;
    const int wvn = __builtin_amdgcn_readfirstlane(threadIdx.x >> 6);
    const int e = (int)swz * WPB + wvn;
    if (e >= E) return;                 // wave-uniform
    const int h = l >> 2;
    const int a = l & 3;

    // segment-constant geometry (uniform loads)
    const int ii = idx_i[(size_t)e * 12];
    const int jj = idx_j[(size_t)e * 12];
    const float pix = pos[ii*3+0], piy = pos[ii*3+1], piz = pos[ii*3+2];
    const float jx = pos[jj*3+0]-pix, jy = pos[jj*3+1]-piy, jz = pos[jj*3+2]-piz;

    // per-lane triplet geometry + angular features -> LDS
    int kj = 0;
    if (l < 12) {
        int t = 12 * e + l;
        kj = idx_kj[t];
        int kk = idx_k[t];
        float kx = pos[kk*3+0]-pix, ky = pos[kk*3+1]-piy, kz = pos[kk*3+2]-piz;
        float aa = jx*kx + jy*ky + jz*kz;
        float cx = jy*kz - jz*ky, cy = jz*kx - jx*kz, cz = jx*ky - jy*kx;
        float bb = sqrtf(cx*cx + cy*cy + cz*cz);
        float ang = atan2f(bb, aa);
        float af0[13];
        af0[0] = ang;
        const float fr[6] = {1.f, 2.f, 3.f, 1.f, 0.5f, 1.f/3.f};
        #pragma unroll
        for (int q = 0; q < 6; ++q)
            __sincosf(ang * fr[q], &af0[1+q], &af0[7+q]);
        #pragma unroll
        for (int c = 0; c < 13; ++c) afL[wvn][l][c] = af0[c];
    }

    const float2 qe  = *(const float2*)&QE [(size_t)e * OUT_DIM + 2*l];
    const float2 ea  = *(const float2*)&EA1[(size_t)e * OUT_DIM + 2*l];
    const float2 erv = *(const float2*)&ERV[(size_t)e * OUT_DIM + 2*l];
    const float qrk2 = QRK2[(size_t)e * NH + h];

    // qwk[c]: per-head projected query against angular key weights
    float qwk[13];
    #pragma unroll
    for (int c = 0; c < 13; ++c) {
        float2 w = *(const float2*)&Wk[(168 + c) * OUT_DIM + 2*l];
        float p = qe.x*w.x + qe.y*w.y;
        p += __shfl_xor(p, 1); p += __shfl_xor(p, 2);
        qwk[c] = p;
    }

    // QK logits (bond part); lane keeps t with t&3==a
    float qk3[3];
    #pragma unroll
    for (int t = 0; t < 12; ++t) {
        int kjt = __builtin_amdgcn_readlane(kj, t);
        float2 kb = *(const float2*)&KB[(size_t)kjt * OUT_DIM + 2*l];
        float v = qe.x*kb.x + qe.y*kb.y;
        v += __shfl_xor(v, 1); v += __shfl_xor(v, 2);
        if ((t & 3) == a) qk3[t >> 2] = v;
    }

    wave_lds_fence();   // af ready

    // angular part + combine
    float lg[3];
    #pragma unroll
    for (int q = 0; q < 3; ++q) {
        int t = a + 4*q;
        float s = 0.f;
        #pragma unroll
        for (int c = 0; c < 13; ++c) s = fmaf(afL[wvn][t][c], qwk[c], s);
        lg[q] = (qk3[q] + s + qrk2) * SCALE;
    }

    // wave-parallel softmax over 12 (per head)
    float m = fmaxf(lg[0], fmaxf(lg[1], lg[2]));
    m = fmaxf(m, __shfl_xor(m, 1)); m = fmaxf(m, __shfl_xor(m, 2));
    float ex0 = __expf(lg[0]-m), ex1 = __expf(lg[1]-m), ex2 = __expf(lg[2]-m);
    float ss = ex0 + ex1 + ex2;
    ss += __shfl_xor(ss, 1); ss += __shfl_xor(ss, 2);
    float inv = 1.f / (ss + 1e-16f);
    float al0 = ex0*inv, al1 = ex1*inv, al2 = ex2*inv;
    float Sh = ss * inv;

    alphaL[wvn][a    ][h] = al0;
    alphaL[wvn][a + 4][h] = al1;
    alphaL[wvn][a + 8][h] = al2;

    // waf[c] = sum_t alpha[t]*af[t][c] (partial over own 3 t, then 4-lane reduce)
    float waf[13];
    #pragma unroll
    for (int c = 0; c < 13; ++c) {
        float wp = al0*afL[wvn][a][c] + al1*afL[wvn][a+4][c] + al2*afL[wvn][a+8][c];
        wp += __shfl_xor(wp, 1); wp += __shfl_xor(wp, 2);
        waf[c] = wp;
    }

    wave_lds_fence();   // alpha ready

    // value accumulation
    float accx = 0.f, accy = 0.f;
    #pragma unroll
    for (int t = 0; t < 12; ++t) {
        int kjt = __builtin_amdgcn_readlane(kj, t);
        float2 vb = *(const float2*)&VB[(size_t)kjt * OUT_DIM + 2*l];
        float alt = alphaL[wvn][t][h];
        accx = fmaf(alt, vb.x, accx);
        accy = fmaf(alt, vb.y, accy);
    }
    float vAx = 0.f, vAy = 0.f;
    #pragma unroll
    for (int c = 0; c < 13; ++c) {
        float2 w = *(const float2*)&Wv[(168 + c) * OUT_DIM + 2*l];
        vAx = fmaf(waf[c], w.x, vAx);
        vAy = fmaf(waf[c], w.y, vAy);
    }
    float2 o;
    o.x = ea.x * (accx + vAx) + erv.x * Sh;
    o.y = ea.y * (accy + vAy) + erv.y * Sh;
    *(float2*)&out[(size_t)e * OUT_DIM + 2*l] = o;
}

// ---------------- generic fallback (unused when T == E*12) ----------------
__global__ __launch_bounds__(128) void attn_generic_kernel(
    const float* __restrict__ pos,
    const int*   __restrict__ idx_i,
    const int*   __restrict__ idx_j,
    const int*   __restrict__ idx_k,
    const int*   __restrict__ idx_kj,
    const int*   __restrict__ idx_ji,
    const float* __restrict__ Wk,
    const float* __restrict__ Wv,
    const float* __restrict__ We1,
    const float* __restrict__ r_feat,
    const float* __restrict__ KB,
    const float* __restrict__ VB,
    const float* __restrict__ QE,
    float* __restrict__ out,
    int E, int T)
{
    __shared__ float rs[NUM_GAUSS];
    __shared__ float af[MAXT][13];
    __shared__ float logit[MAXT][NH];
    __shared__ float qwk[NH][13];
    __shared__ float waf[NH][13];
    __shared__ int   kjs[MAXT];
    __shared__ float qrk2s[NH];
    __shared__ float Shs[NH];

    const int e = blockIdx.x;
    const int d = threadIdx.x;
    const int h8 = d >> 3;

    int l = 0, hi = T;
    while (l < hi) { int mid = (l + hi) >> 1; if (idx_ji[mid] < e) l = mid + 1; else hi = mid; }
    int lo = l, c2 = 0;
    while (lo + c2 < T && c2 < MAXT && idx_ji[lo + c2] == e) ++c2;
    int cnt = c2;

    if (d < NUM_GAUSS) rs[d] = r_feat[(size_t)e * NUM_GAUSS + d];
    if (d < cnt) {
        int t = lo + d;
        kjs[d] = idx_kj[t];
        int ii = idx_i[t], jj = idx_j[t], kk = idx_k[t];
        float pix = pos[ii*3+0], piy = pos[ii*3+1], piz = pos[ii*3+2];
        float jx = pos[jj*3+0]-pix, jy = pos[jj*3+1]-piy, jz = pos[jj*3+2]-piz;
        float kx = pos[kk*3+0]-pix, ky = pos[kk*3+1]-piy, kz = pos[kk*3+2]-piz;
        float aa = jx*kx + jy*ky + jz*kz;
        float cx = jy*kz - jz*ky, cy = jz*kx - jx*kz, cz = jx*ky - jy*kx;
        float bb = sqrtf(cx*cx + cy*cy + cz*cz);
        float ang = atan2f(bb, aa);
        af[d][0] = ang;
        const float fr[6] = {1.f, 2.f, 3.f, 1.f, 0.5f, 1.f/3.f};
        #pragma unroll
        for (int q = 0; q < 6; ++q) {
            float s, cc;
            __sincosf(ang * fr[q], &s, &cc);
            af[d][1 + q] = s;
            af[d][7 + q] = cc;
        }
    }
    __syncthreads();

    const float qe = QE[(size_t)e * OUT_DIM + d];
    float s1 = 0.f, sk = 0.f, sv = 0.f;
    #pragma unroll
    for (int g = 0; g < NUM_GAUSS; ++g) {
        float rg = rs[g];
        s1 = fmaf(rg, We1[g * OUT_DIM + d], s1);
        sk = fmaf(rg, Wk[(148 + g) * OUT_DIM + d], sk);
        sv = fmaf(rg, Wv[(148 + g) * OUT_DIM + d], sv);
    }
    const float ea1 = tanhf(s1);
    const float rv2 = sv;

    {
        float v = qe * sk;
        v += __shfl_xor(v, 1, 8); v += __shfl_xor(v, 2, 8); v += __shfl_xor(v, 4, 8);
        if ((d & 7) == 0) qrk2s[h8] = v;
    }
    {
        float p[13];
        #pragma unroll
        for (int c = 0; c < 13; ++c) p[c] = qe * Wk[(168 + c) * OUT_DIM + d];
        #pragma unroll
        for (int c = 0; c < 13; ++c) {
            float v = p[c];
            v += __shfl_xor(v, 1, 8); v += __shfl_xor(v, 2, 8); v += __shfl_xor(v, 4, 8);
            if ((d & 7) == 0) qwk[h8][c] = v;
        }
    }
    for (int t = 0; t < cnt; ++t) {
        float lv = qe * KB[(size_t)kjs[t] * OUT_DIM + d];
        lv += __shfl_xor(lv, 1, 8); lv += __shfl_xor(lv, 2, 8); lv += __shfl_xor(lv, 4, 8);
        if ((d & 7) == 0) logit[t][h8] = lv;
    }
    __syncthreads();
    {
        const int hh = d & 15;
        for (int t = d >> 4; t < cnt; t += 8) {
            float s = 0.f;
            #pragma unroll
            for (int c = 0; c < 13; ++c) s = fmaf(af[t][c], qwk[hh][c], s);
            logit[t][hh] = (logit[t][hh] + s + qrk2s[hh]) * SCALE;
        }
    }
    __syncthreads();
    if (d < NH) {
        float m = -1e30f;
        for (int t = 0; t < cnt; ++t) m = fmaxf(m, logit[t][d]);
        float s = 0.f;
        for (int t = 0; t < cnt; ++t) { float ex = __expf(logit[t][d] - m); logit[t][d] = ex; s += ex; }
        float inv = 1.f / (s + 1e-16f);
        for (int t = 0; t < cnt; ++t) logit[t][d] *= inv;
        Shs[d] = s * inv;
    }
    __syncthreads();
    {
        const int hh = d & 15;
        int c = d >> 4;
        float w1 = 0.f;
        for (int t = 0; t < cnt; ++t) w1 = fmaf(logit[t][hh], af[t][c], w1);
        waf[hh][c] = w1;
        c += 8;
        if (c < 13) {
            float w2 = 0.f;
            for (int t = 0; t < cnt; ++t) w2 = fmaf(logit[t][hh], af[t][c], w2);
            waf[hh][c] = w2;
        }
    }
    __syncthreads();
    float vA = 0.f;
    #pragma unroll
    for (int c = 0; c < 13; ++c) vA = fmaf(waf[h8][c], Wv[(168 + c) * OUT_DIM + d], vA);
    float acc = 0.f;
    for (int t = 0; t < cnt; ++t)
        acc = fmaf(logit[t][h8], VB[(size_t)kjs[t] * OUT_DIM + d], acc);
    out[(size_t)e * OUT_DIM + d] = ea1 * (acc + vA + rv2 * Shs[h8]);
}

extern "C" void kernel_launch(void* const* d_in, const int* in_sizes, int n_in,
                              void* d_out, int out_size, void* d_ws, size_t ws_size,
                              hipStream_t stream) {
    const float* h_bond = (const float*)d_in[1];
    const float* pos    = (const float*)d_in[2];
    const int*   bidx   = (const int*)d_in[3];
    const int*   idx_i  = (const int*)d_in[4];
    const int*   idx_j  = (const int*)d_in[5];
    const int*   idx_k  = (const int*)d_in[6];
    const int*   idx_kj = (const int*)d_in[7];
    const int*   idx_ji = (const int*)d_in[8];
    const float* Wk     = (const float*)d_in[9];
    const float* Wv     = (const float*)d_in[10];
    const float* Wq     = (const float*)d_in[11];
    const float* We0    = (const float*)d_in[12];
    const float* We1    = (const float*)d_in[13];

    const int E = in_sizes[1] / INPUT_DIM;
    const int T = in_sizes[4];

    float* ws = (float*)d_ws;
    float* r_feat = ws;                               // E*20
    float* KB   = r_feat + (size_t)E * NUM_GAUSS;     // E*128
    float* VB   = KB   + (size_t)E * OUT_DIM;         // E*128
    float* QE   = VB   + (size_t)E * OUT_DIM;         // E*128
    float* EA1  = QE   + (size_t)E * OUT_DIM;         // E*128
    float* ERV  = EA1  + (size_t)E * OUT_DIM;         // E*128
    float* QRK2 = ERV  + (size_t)E * OUT_DIM;         // E*16
    // total: E*(20 + 5*128 + 16)*4 B  (~133 MB for E=49152)

    rbf_kernel<<<(E + 255) / 256, 256, 0, stream>>>(pos, bidx, r_feat, E);

    bond_proj_kernel<<<(E + BM - 1) / BM, 256, 0, stream>>>(
        h_bond, r_feat, Wk, Wv, Wq, We0, We1, KB, VB, QE, EA1, ERV, QRK2, E);

    if (T == E * 12) {
        attn_wave_kernel<<<(E + WPB - 1) / WPB, 64 * WPB, 0, stream>>>(
            pos, idx_i, idx_j, idx_k, idx_kj,
            Wk, Wv, KB, VB, QE, EA1, ERV, QRK2, (float*)d_out, E);
    } else {
        attn_generic_kernel<<<E, 128, 0, stream>>>(
            pos, idx_i, idx_j, idx_k, idx_kj, idx_ji,
            Wk, Wv, We1, r_feat, KB, VB, QE, (float*)d_out, E, T);
    }
}

// Round 7
// 330.148 us; speedup vs baseline: 2.3338x; 2.3338x over previous
//
#include <hip/hip_runtime.h>
#include <math.h>

#define INPUT_DIM 128
#define OUT_DIM 128
#define NUM_GAUSS 20
#define NH 16
#define BM 64      // bonds per block in bond_proj
#define AST 148    // LDS row stride (scalar b32 reads, broadcast)
#define MAXT 16
#define WPB 4      // waves (segments) per block in attn_wave
#define SCALE 0.35355339059327373f

// W_key/W_value row layout: [0:128) h_bond(kj), [128:148) r_kj, [148:168) r_ji, [168:181) a_feat

#define W4(P, r) (*(const float4*)&(P)[(size_t)(r) * OUT_DIM + dn])

static __device__ __forceinline__ void wave_lds_fence() {
    __asm__ volatile("s_waitcnt lgkmcnt(0)" ::: "memory");
    __builtin_amdgcn_wave_barrier();
}

// 4-pass register-tiled GEMM, <=64 live accumulators per pass, explicit
// 1-deep weight prefetch. RBF staging fused (computes gaussians inline).
__global__ __launch_bounds__(256, 3) void bond_proj_kernel(
    const float* __restrict__ h_bond,
    const float* __restrict__ pos,
    const int*   __restrict__ bond_index,
    const float* __restrict__ Wk,
    const float* __restrict__ Wv,
    const float* __restrict__ Wq,
    const float* __restrict__ We0,
    const float* __restrict__ We1,
    float* __restrict__ r_out,
    float* __restrict__ KB,
    float* __restrict__ VB,
    float* __restrict__ QE,
    float* __restrict__ EA1,
    float* __restrict__ ERV,
    float* __restrict__ QRK2,
    int E)
{
    __shared__ float As[BM * AST];
    const int tid = threadIdx.x;
    const int e0 = blockIdx.x * BM;

    // stage h (64x128) via float4
    for (int i = tid; i < BM * 32; i += 256) {
        int e = i >> 5, c = (i & 31) << 2;
        float4 v = make_float4(0.f, 0.f, 0.f, 0.f);
        if (e0 + e < E) v = *(const float4*)&h_bond[(size_t)(e0 + e) * INPUT_DIM + c];
        float* dst = &As[e * AST + c];
        dst[0] = v.x; dst[1] = v.y; dst[2] = v.z; dst[3] = v.w;
    }
    // stage r (64x20), computed inline (rbf fused)
    {
        const float step = 10.f / (NUM_GAUSS - 1);
        const float coeff = -0.5f / (step * step);
        for (int i = tid; i < BM * NUM_GAUSS; i += 256) {
            int e = i / NUM_GAUSS, g = i % NUM_GAUSS;
            int ge = e0 + e;
            float rv = 0.f;
            if (ge < E) {
                int jrow = bond_index[ge];
                int icol = bond_index[E + ge];
                float dx = pos[icol*3+0] - pos[jrow*3+0];
                float dy = pos[icol*3+1] - pos[jrow*3+1];
                float dz = pos[icol*3+2] - pos[jrow*3+2];
                float dist = sqrtf(dx*dx + dy*dy + dz*dz);
                float t = dist - g * step;
                rv = __expf(coeff * t * t);
                r_out[(size_t)ge * NUM_GAUSS + g] = rv;
            }
            As[e * AST + 128 + g] = rv;
        }
    }
    __syncthreads();

    const int em = tid >> 5;          // bond group: bonds em*8 .. em*8+7
    const int dn = (tid & 31) << 2;   // dim group: dims dn .. dn+3
    const float* AsB = &As[em * 8 * AST];

    // ---- pass 1: K and V (K = 148), 64 accs ----
    {
        float aK[8][4], aV[8][4];
        #pragma unroll
        for (int m = 0; m < 8; ++m)
            #pragma unroll
            for (int j = 0; j < 4; ++j) { aK[m][j] = 0.f; aV[m][j] = 0.f; }

        float4 wk = W4(Wk, 0), wv = W4(Wv, 0);
        for (int c = 0; c < 148; ++c) {
            float4 nk = wk, nv = wv;
            if (c + 1 < 148) { nk = W4(Wk, c + 1); nv = W4(Wv, c + 1); }
            #pragma unroll
            for (int m = 0; m < 8; ++m) {
                float a = AsB[m * AST + c];      // wave-broadcast LDS read
                aK[m][0] = fmaf(a, wk.x, aK[m][0]); aK[m][1] = fmaf(a, wk.y, aK[m][1]);
                aK[m][2] = fmaf(a, wk.z, aK[m][2]); aK[m][3] = fmaf(a, wk.w, aK[m][3]);
                aV[m][0] = fmaf(a, wv.x, aV[m][0]); aV[m][1] = fmaf(a, wv.y, aV[m][1]);
                aV[m][2] = fmaf(a, wv.z, aV[m][2]); aV[m][3] = fmaf(a, wv.w, aV[m][3]);
            }
            wk = nk; wv = nv;
        }
        #pragma unroll
        for (int m = 0; m < 8; ++m) {
            int e = e0 + em * 8 + m;
            if (e < E) {
                *(float4*)&KB[(size_t)e * OUT_DIM + dn] =
                    make_float4(aK[m][0], aK[m][1], aK[m][2], aK[m][3]);
                *(float4*)&VB[(size_t)e * OUT_DIM + dn] =
                    make_float4(aV[m][0], aV[m][1], aV[m][2], aV[m][3]);
            }
        }
    }

    // ---- pass 2: QE = (h@Wq) * tanh(r@We0), 64 accs ----
    {
        float aQ[8][4], aE[8][4];
        #pragma unroll
        for (int m = 0; m < 8; ++m)
            #pragma unroll
            for (int j = 0; j < 4; ++j) { aQ[m][j] = 0.f; aE[m][j] = 0.f; }

        float4 wq = W4(Wq, 0);
        for (int c = 0; c < 128; ++c) {
            float4 nq = wq;
            if (c + 1 < 128) nq = W4(Wq, c + 1);
            #pragma unroll
            for (int m = 0; m < 8; ++m) {
                float a = AsB[m * AST + c];
                aQ[m][0] = fmaf(a, wq.x, aQ[m][0]); aQ[m][1] = fmaf(a, wq.y, aQ[m][1]);
                aQ[m][2] = fmaf(a, wq.z, aQ[m][2]); aQ[m][3] = fmaf(a, wq.w, aQ[m][3]);
            }
            wq = nq;
        }
        float4 w0 = W4(We0, 0);
        for (int g = 0; g < 20; ++g) {
            float4 n0 = w0;
            if (g + 1 < 20) n0 = W4(We0, g + 1);
            #pragma unroll
            for (int m = 0; m < 8; ++m) {
                float a = AsB[m * AST + 128 + g];
                aE[m][0] = fmaf(a, w0.x, aE[m][0]); aE[m][1] = fmaf(a, w0.y, aE[m][1]);
                aE[m][2] = fmaf(a, w0.z, aE[m][2]); aE[m][3] = fmaf(a, w0.w, aE[m][3]);
            }
            w0 = n0;
        }
        #pragma unroll
        for (int m = 0; m < 8; ++m) {
            int e = e0 + em * 8 + m;
            if (e < E)
                *(float4*)&QE[(size_t)e * OUT_DIM + dn] =
                    make_float4(aQ[m][0] * tanhf(aE[m][0]), aQ[m][1] * tanhf(aE[m][1]),
                                aQ[m][2] * tanhf(aE[m][2]), aQ[m][3] * tanhf(aE[m][3]));
        }
    }

    // ---- pass 3: EA1 = tanh(r@We1), ERV = EA1 * (r@Wv[148:168]), 64 accs ----
    {
        float a1[8][4], aS[8][4];
        #pragma unroll
        for (int m = 0; m < 8; ++m)
            #pragma unroll
            for (int j = 0; j < 4; ++j) { a1[m][j] = 0.f; aS[m][j] = 0.f; }

        float4 w1 = W4(We1, 0), wsv = W4(Wv, 148);
        for (int g = 0; g < 20; ++g) {
            float4 n1 = w1, nv = wsv;
            if (g + 1 < 20) { n1 = W4(We1, g + 1); nv = W4(Wv, 148 + g + 1); }
            #pragma unroll
            for (int m = 0; m < 8; ++m) {
                float a = AsB[m * AST + 128 + g];
                a1[m][0] = fmaf(a, w1.x, a1[m][0]); a1[m][1] = fmaf(a, w1.y, a1[m][1]);
                a1[m][2] = fmaf(a, w1.z, a1[m][2]); a1[m][3] = fmaf(a, w1.w, a1[m][3]);
                aS[m][0] = fmaf(a, wsv.x, aS[m][0]); aS[m][1] = fmaf(a, wsv.y, aS[m][1]);
                aS[m][2] = fmaf(a, wsv.z, aS[m][2]); aS[m][3] = fmaf(a, wsv.w, aS[m][3]);
            }
            w1 = n1; wsv = nv;
        }
        #pragma unroll
        for (int m = 0; m < 8; ++m) {
            int e = e0 + em * 8 + m;
            if (e < E) {
                float t0 = tanhf(a1[m][0]), t1 = tanhf(a1[m][1]);
                float t2 = tanhf(a1[m][2]), t3 = tanhf(a1[m][3]);
                *(float4*)&EA1[(size_t)e * OUT_DIM + dn] = make_float4(t0, t1, t2, t3);
                *(float4*)&ERV[(size_t)e * OUT_DIM + dn] =
                    make_float4(t0 * aS[m][0], t1 * aS[m][1], t2 * aS[m][2], t3 * aS[m][3]);
            }
        }
    }

    // ---- pass 4: RK2 = r@Wk[148:168] (regs only) -> QRK2[e][16], 32 accs ----
    {
        float aR[8][4];
        #pragma unroll
        for (int m = 0; m < 8; ++m)
            #pragma unroll
            for (int j = 0; j < 4; ++j) aR[m][j] = 0.f;

        float4 wkr = W4(Wk, 148);
        for (int g = 0; g < 20; ++g) {
            float4 nk = wkr;
            if (g + 1 < 20) nk = W4(Wk, 148 + g + 1);
            #pragma unroll
            for (int m = 0; m < 8; ++m) {
                float a = AsB[m * AST + 128 + g];
                aR[m][0] = fmaf(a, wkr.x, aR[m][0]); aR[m][1] = fmaf(a, wkr.y, aR[m][1]);
                aR[m][2] = fmaf(a, wkr.z, aR[m][2]); aR[m][3] = fmaf(a, wkr.w, aR[m][3]);
            }
            wkr = nk;
        }
        const int hh = (tid & 31) >> 1;   // head owning dims dn..dn+3 (with partner lane)
        #pragma unroll
        for (int m = 0; m < 8; ++m) {
            int e = e0 + em * 8 + m;
            float s = 0.f;
            if (e < E) {
                // same-thread RAW on QE (written in pass 2): L2-warm reload
                float4 q = *(const float4*)&QE[(size_t)e * OUT_DIM + dn];
                s = q.x*aR[m][0] + q.y*aR[m][1] + q.z*aR[m][2] + q.w*aR[m][3];
            }
            s += __shfl_xor(s, 1);
            if ((tid & 1) == 0 && e < E) QRK2[(size_t)e * NH + hh] = s;
        }
    }
}

// One 64-lane wave per segment; lane l owns dims (2l, 2l+1); head h = l>>2.
__global__ __launch_bounds__(256, 2) void attn_wave_kernel(
    const float* __restrict__ pos,
    const int*   __restrict__ idx_i,
    const int*   __restrict__ idx_j,
    const int*   __restrict__ idx_k,
    const int*   __restrict__ idx_kj,
    const float* __restrict__ Wk,
    const float* __restrict__ Wv,
    const float* __restrict__ KB,
    const float* __restrict__ VB,
    const float* __restrict__ QE,
    const float* __restrict__ EA1,
    const float* __restrict__ ERV,
    const float* __restrict__ QRK2,
    float* __restrict__ out,
    int E)
{
    __shared__ float afL[WPB][12][13];
    __shared__ float alphaL[WPB][12][16];

    // bijective XCD-aware swizzle: contiguous block ranges per XCD (m204)
    unsigned bid = blockIdx.x, nwg = gridDim.x;
    unsigned qq = nwg >> 3, rr = nwg & 7, xc = bid & 7, rest = bid >> 3;
    unsigned swz = (xc < rr ? xc * (qq + 1) : rr * (qq + 1) + (xc - rr) * qq) + rest;

    const int l = threadIdx.x & 63;
    const int wvn = __builtin_amdgcn_readfirstlane(threadIdx.x >> 6);
    const int e = (int)swz * WPB + wvn;
    if (e >= E) return;                 // wave-uniform
    const int h = l >> 2;
    const int a = l & 3;

    // segment-constant geometry (uniform loads)
    const int ii = idx_i[(size_t)e * 12];
    const int jj = idx_j[(size_t)e * 12];
    const float pix = pos[ii*3+0], piy = pos[ii*3+1], piz = pos[ii*3+2];
    const float jx = pos[jj*3+0]-pix, jy = pos[jj*3+1]-piy, jz = pos[jj*3+2]-piz;

    // per-lane triplet geometry + angular features -> LDS
    int kj = 0;
    if (l < 12) {
        int t = 12 * e + l;
        kj = idx_kj[t];
        int kk = idx_k[t];
        float kx = pos[kk*3+0]-pix, ky = pos[kk*3+1]-piy, kz = pos[kk*3+2]-piz;
        float aa = jx*kx + jy*ky + jz*kz;
        float cx = jy*kz - jz*ky, cy = jz*kx - jx*kz, cz = jx*ky - jy*kx;
        float bb = sqrtf(cx*cx + cy*cy + cz*cz);
        float ang = atan2f(bb, aa);
        float af0[13];
        af0[0] = ang;
        const float fr[6] = {1.f, 2.f, 3.f, 1.f, 0.5f, 1.f/3.f};
        #pragma unroll
        for (int q = 0; q < 6; ++q)
            __sincosf(ang * fr[q], &af0[1+q], &af0[7+q]);
        #pragma unroll
        for (int c = 0; c < 13; ++c) afL[wvn][l][c] = af0[c];
    }

    const float2 qe  = *(const float2*)&QE [(size_t)e * OUT_DIM + 2*l];
    const float2 ea  = *(const float2*)&EA1[(size_t)e * OUT_DIM + 2*l];
    const float2 erv = *(const float2*)&ERV[(size_t)e * OUT_DIM + 2*l];
    const float qrk2 = QRK2[(size_t)e * NH + h];

    // qwk[c]: per-head projected query against angular key weights
    float qwk[13];
    #pragma unroll
    for (int c = 0; c < 13; ++c) {
        float2 w = *(const float2*)&Wk[(168 + c) * OUT_DIM + 2*l];
        float p = qe.x*w.x + qe.y*w.y;
        p += __shfl_xor(p, 1); p += __shfl_xor(p, 2);
        qwk[c] = p;
    }

    // QK logits (bond part); lane keeps t with t&3==a
    float qk3[3];
    #pragma unroll
    for (int t = 0; t < 12; ++t) {
        int kjt = __builtin_amdgcn_readlane(kj, t);
        float2 kb = *(const float2*)&KB[(size_t)kjt * OUT_DIM + 2*l];
        float v = qe.x*kb.x + qe.y*kb.y;
        v += __shfl_xor(v, 1); v += __shfl_xor(v, 2);
        if ((t & 3) == a) qk3[t >> 2] = v;
    }

    wave_lds_fence();   // af ready

    // angular part + combine
    float lg[3];
    #pragma unroll
    for (int q = 0; q < 3; ++q) {
        int t = a + 4*q;
        float s = 0.f;
        #pragma unroll
        for (int c = 0; c < 13; ++c) s = fmaf(afL[wvn][t][c], qwk[c], s);
        lg[q] = (qk3[q] + s + qrk2) * SCALE;
    }

    // wave-parallel softmax over 12 (per head)
    float m = fmaxf(lg[0], fmaxf(lg[1], lg[2]));
    m = fmaxf(m, __shfl_xor(m, 1)); m = fmaxf(m, __shfl_xor(m, 2));
    float ex0 = __expf(lg[0]-m), ex1 = __expf(lg[1]-m), ex2 = __expf(lg[2]-m);
    float ss = ex0 + ex1 + ex2;
    ss += __shfl_xor(ss, 1); ss += __shfl_xor(ss, 2);
    float inv = 1.f / (ss + 1e-16f);
    float al0 = ex0*inv, al1 = ex1*inv, al2 = ex2*inv;
    float Sh = ss * inv;

    alphaL[wvn][a    ][h] = al0;
    alphaL[wvn][a + 4][h] = al1;
    alphaL[wvn][a + 8][h] = al2;

    // waf[c] = sum_t alpha[t]*af[t][c] (partial over own 3 t, then 4-lane reduce)
    float waf[13];
    #pragma unroll
    for (int c = 0; c < 13; ++c) {
        float wp = al0*afL[wvn][a][c] + al1*afL[wvn][a+4][c] + al2*afL[wvn][a+8][c];
        wp += __shfl_xor(wp, 1); wp += __shfl_xor(wp, 2);
        waf[c] = wp;
    }

    wave_lds_fence();   // alpha ready

    // value accumulation
    float accx = 0.f, accy = 0.f;
    #pragma unroll
    for (int t = 0; t < 12; ++t) {
        int kjt = __builtin_amdgcn_readlane(kj, t);
        float2 vb = *(const float2*)&VB[(size_t)kjt * OUT_DIM + 2*l];
        float alt = alphaL[wvn][t][h];
        accx = fmaf(alt, vb.x, accx);
        accy = fmaf(alt, vb.y, accy);
    }
    float vAx = 0.f, vAy = 0.f;
    #pragma unroll
    for (int c = 0; c < 13; ++c) {
        float2 w = *(const float2*)&Wv[(168 + c) * OUT_DIM + 2*l];
        vAx = fmaf(waf[c], w.x, vAx);
        vAy = fmaf(waf[c], w.y, vAy);
    }
    float2 o;
    o.x = ea.x * (accx + vAx) + erv.x * Sh;
    o.y = ea.y * (accy + vAy) + erv.y * Sh;
    *(float2*)&out[(size_t)e * OUT_DIM + 2*l] = o;
}

// ---------------- generic fallback (unused when T == E*12) ----------------
__global__ __launch_bounds__(128) void attn_generic_kernel(
    const float* __restrict__ pos,
    const int*   __restrict__ idx_i,
    const int*   __restrict__ idx_j,
    const int*   __restrict__ idx_k,
    const int*   __restrict__ idx_kj,
    const int*   __restrict__ idx_ji,
    const float* __restrict__ Wk,
    const float* __restrict__ Wv,
    const float* __restrict__ We1,
    const float* __restrict__ r_feat,
    const float* __restrict__ KB,
    const float* __restrict__ VB,
    const float* __restrict__ QE,
    float* __restrict__ out,
    int E, int T)
{
    __shared__ float rs[NUM_GAUSS];
    __shared__ float af[MAXT][13];
    __shared__ float logit[MAXT][NH];
    __shared__ float qwk[NH][13];
    __shared__ float waf[NH][13];
    __shared__ int   kjs[MAXT];
    __shared__ float qrk2s[NH];
    __shared__ float Shs[NH];

    const int e = blockIdx.x;
    const int d = threadIdx.x;
    const int h8 = d >> 3;

    int l = 0, hi = T;
    while (l < hi) { int mid = (l + hi) >> 1; if (idx_ji[mid] < e) l = mid + 1; else hi = mid; }
    int lo = l, c2 = 0;
    while (lo + c2 < T && c2 < MAXT && idx_ji[lo + c2] == e) ++c2;
    int cnt = c2;

    if (d < NUM_GAUSS) rs[d] = r_feat[(size_t)e * NUM_GAUSS + d];
    if (d < cnt) {
        int t = lo + d;
        kjs[d] = idx_kj[t];
        int ii = idx_i[t], jj = idx_j[t], kk = idx_k[t];
        float pix = pos[ii*3+0], piy = pos[ii*3+1], piz = pos[ii*3+2];
        float jx = pos[jj*3+0]-pix, jy = pos[jj*3+1]-piy, jz = pos[jj*3+2]-piz;
        float kx = pos[kk*3+0]-pix, ky = pos[kk*3+1]-piy, kz = pos[kk*3+2]-piz;
        float aa = jx*kx + jy*ky + jz*kz;
        float cx = jy*kz - jz*ky, cy = jz*kx - jx*kz, cz = jx*ky - jy*kx;
        float bb = sqrtf(cx*cx + cy*cy + cz*cz);
        float ang = atan2f(bb, aa);
        af[d][0] = ang;
        const float fr[6] = {1.f, 2.f, 3.f, 1.f, 0.5f, 1.f/3.f};
        #pragma unroll
        for (int q = 0; q < 6; ++q) {
            float s, cc;
            __sincosf(ang * fr[q], &s, &cc);
            af[d][1 + q] = s;
            af[d][7 + q] = cc;
        }
    }
    __syncthreads();

    const float qe = QE[(size_t)e * OUT_DIM + d];
    float s1 = 0.f, sk = 0.f, sv = 0.f;
    #pragma unroll
    for (int g = 0; g < NUM_GAUSS; ++g) {
        float rg = rs[g];
        s1 = fmaf(rg, We1[g * OUT_DIM + d], s1);
        sk = fmaf(rg, Wk[(148 + g) * OUT_DIM + d], sk);
        sv = fmaf(rg, Wv[(148 + g) * OUT_DIM + d], sv);
    }
    const float ea1 = tanhf(s1);
    const float rv2 = sv;

    {
        float v = qe * sk;
        v += __shfl_xor(v, 1, 8); v += __shfl_xor(v, 2, 8); v += __shfl_xor(v, 4, 8);
        if ((d & 7) == 0) qrk2s[h8] = v;
    }
    {
        float p[13];
        #pragma unroll
        for (int c = 0; c < 13; ++c) p[c] = qe * Wk[(168 + c) * OUT_DIM + d];
        #pragma unroll
        for (int c = 0; c < 13; ++c) {
            float v = p[c];
            v += __shfl_xor(v, 1, 8); v += __shfl_xor(v, 2, 8); v += __shfl_xor(v, 4, 8);
            if ((d & 7) == 0) qwk[h8][c] = v;
        }
    }
    for (int t = 0; t < cnt; ++t) {
        float lv = qe * KB[(size_t)kjs[t] * OUT_DIM + d];
        lv += __shfl_xor(lv, 1, 8); lv += __shfl_xor(lv, 2, 8); lv += __shfl_xor(lv, 4, 8);
        if ((d & 7) == 0) logit[t][h8] = lv;
    }
    __syncthreads();
    {
        const int hh = d & 15;
        for (int t = d >> 4; t < cnt; t += 8) {
            float s = 0.f;
            #pragma unroll
            for (int c = 0; c < 13; ++c) s = fmaf(af[t][c], qwk[hh][c], s);
            logit[t][hh] = (logit[t][hh] + s + qrk2s[hh]) * SCALE;
        }
    }
    __syncthreads();
    if (d < NH) {
        float m = -1e30f;
        for (int t = 0; t < cnt; ++t) m = fmaxf(m, logit[t][d]);
        float s = 0.f;
        for (int t = 0; t < cnt; ++t) { float ex = __expf(logit[t][d] - m); logit[t][d] = ex; s += ex; }
        float inv = 1.f / (s + 1e-16f);
        for (int t = 0; t < cnt; ++t) logit[t][d] *= inv;
        Shs[d] = s * inv;
    }
    __syncthreads();
    {
        const int hh = d & 15;
        int c = d >> 4;
        float w1 = 0.f;
        for (int t = 0; t < cnt; ++t) w1 = fmaf(logit[t][hh], af[t][c], w1);
        waf[hh][c] = w1;
        c += 8;
        if (c < 13) {
            float w2 = 0.f;
            for (int t = 0; t < cnt; ++t) w2 = fmaf(logit[t][hh], af[t][c], w2);
            waf[hh][c] = w2;
        }
    }
    __syncthreads();
    float vA = 0.f;
    #pragma unroll
    for (int c = 0; c < 13; ++c) vA = fmaf(waf[h8][c], Wv[(168 + c) * OUT_DIM + d], vA);
    float acc = 0.f;
    for (int t = 0; t < cnt; ++t)
        acc = fmaf(logit[t][h8], VB[(size_t)kjs[t] * OUT_DIM + d], acc);
    out[(size_t)e * OUT_DIM + d] = ea1 * (acc + vA + rv2 * Shs[h8]);
}

extern "C" void kernel_launch(void* const* d_in, const int* in_sizes, int n_in,
                              void* d_out, int out_size, void* d_ws, size_t ws_size,
                              hipStream_t stream) {
    const float* h_bond = (const float*)d_in[1];
    const float* pos    = (const float*)d_in[2];
    const int*   bidx   = (const int*)d_in[3];
    const int*   idx_i  = (const int*)d_in[4];
    const int*   idx_j  = (const int*)d_in[5];
    const int*   idx_k  = (const int*)d_in[6];
    const int*   idx_kj = (const int*)d_in[7];
    const int*   idx_ji = (const int*)d_in[8];
    const float* Wk     = (const float*)d_in[9];
    const float* Wv     = (const float*)d_in[10];
    const float* Wq     = (const float*)d_in[11];
    const float* We0    = (const float*)d_in[12];
    const float* We1    = (const float*)d_in[13];

    const int E = in_sizes[1] / INPUT_DIM;
    const int T = in_sizes[4];

    float* ws = (float*)d_ws;
    float* r_feat = ws;                               // E*20
    float* KB   = r_feat + (size_t)E * NUM_GAUSS;     // E*128
    float* VB   = KB   + (size_t)E * OUT_DIM;         // E*128
    float* QE   = VB   + (size_t)E * OUT_DIM;         // E*128
    float* EA1  = QE   + (size_t)E * OUT_DIM;         // E*128
    float* ERV  = EA1  + (size_t)E * OUT_DIM;         // E*128
    float* QRK2 = ERV  + (size_t)E * OUT_DIM;         // E*16
    // total: E*(20 + 5*128 + 16)*4 B  (~133 MB for E=49152)

    bond_proj_kernel<<<(E + BM - 1) / BM, 256, 0, stream>>>(
        h_bond, pos, bidx, Wk, Wv, Wq, We0, We1,
        r_feat, KB, VB, QE, EA1, ERV, QRK2, E);

    if (T == E * 12) {
        attn_wave_kernel<<<(E + WPB - 1) / WPB, 64 * WPB, 0, stream>>>(
            pos, idx_i, idx_j, idx_k, idx_kj,
            Wk, Wv, KB, VB, QE, EA1, ERV, QRK2, (float*)d_out, E);
    } else {
        attn_generic_kernel<<<E, 128, 0, stream>>>(
            pos, idx_i, idx_j, idx_k, idx_kj, idx_ji,
            Wk, Wv, We1, r_feat, KB, VB, QE, (float*)d_out, E, T);
    }
}

// Round 8
// 192.880 us; speedup vs baseline: 3.9948x; 1.7117x over previous
//
#include <hip/hip_runtime.h>
#include <math.h>

#define INPUT_DIM 128
#define OUT_DIM 128
#define NUM_GAUSS 20
#define NH 16
#define BM 64      // bonds per block in bond_proj / redge
#define MAXT 16
#define WPB 4      // waves (segments) per block in attn_wave
#define SCALE 0.35355339059327373f

// W_key/W_value row layout: [0:128) h_bond(kj), [128:148) r_kj, [148:168) r_ji, [168:181) a_feat

static __device__ __forceinline__ void wave_lds_fence() {
    __asm__ volatile("s_waitcnt lgkmcnt(0)" ::: "memory");
    __builtin_amdgcn_wave_barrier();
}

__global__ __launch_bounds__(256) void rbf_kernel(
    const float* __restrict__ pos,
    const int*   __restrict__ bond_index,
    float* __restrict__ r_out,
    int E)
{
    int e = blockIdx.x * 256 + threadIdx.x;
    if (e >= E) return;
    int jrow = bond_index[e];
    int icol = bond_index[E + e];
    float dx = pos[icol*3+0] - pos[jrow*3+0];
    float dy = pos[icol*3+1] - pos[jrow*3+1];
    float dz = pos[icol*3+2] - pos[jrow*3+2];
    float dist = sqrtf(dx*dx + dy*dy + dz*dz);
    const float step = 10.f / (NUM_GAUSS - 1);
    const float coeff = -0.5f / (step * step);
    float v[NUM_GAUSS];
    #pragma unroll
    for (int g = 0; g < NUM_GAUSS; ++g) {
        float t = dist - g * step;
        v[g] = __expf(coeff * t * t);
    }
    float4* o = (float4*)&r_out[(size_t)e * NUM_GAUSS];
    #pragma unroll
    for (int q = 0; q < 5; ++q)
        o[q] = make_float4(v[4*q], v[4*q+1], v[4*q+2], v[4*q+3]);
}

// R4-proven register-tiled GEMM: block = 64 bonds x 128 dims; thread = 8 bonds x 4 dims.
// Single interleaved k-loop producing K/V/Q/E0; compiler schedules it well (~60us).
__global__ __launch_bounds__(256, 3) void bond_proj_kernel(
    const float* __restrict__ h_bond,
    const float* __restrict__ r_feat,
    const float* __restrict__ Wk,
    const float* __restrict__ Wv,
    const float* __restrict__ Wq,
    const float* __restrict__ We0,
    float* __restrict__ KB,
    float* __restrict__ VB,
    float* __restrict__ QE,
    int E)
{
    __shared__ float As[BM * 148];
    const int tid = threadIdx.x;
    const int e0 = blockIdx.x * BM;

    // stage h (64x128) + r (64x20) into LDS
    for (int i = tid; i < BM * 32; i += 256) {
        int e = i >> 5, c = (i & 31) << 2;
        float4 v = make_float4(0.f, 0.f, 0.f, 0.f);
        if (e0 + e < E) v = *(const float4*)&h_bond[(size_t)(e0 + e) * INPUT_DIM + c];
        float* dst = &As[e * 148 + c];
        dst[0] = v.x; dst[1] = v.y; dst[2] = v.z; dst[3] = v.w;
    }
    for (int i = tid; i < BM * 5; i += 256) {
        int e = i / 5, q = (i % 5) << 2;
        float4 v = make_float4(0.f, 0.f, 0.f, 0.f);
        if (e0 + e < E) v = *(const float4*)&r_feat[(size_t)(e0 + e) * NUM_GAUSS + q];
        float* dst = &As[e * 148 + 128 + q];
        dst[0] = v.x; dst[1] = v.y; dst[2] = v.z; dst[3] = v.w;
    }
    __syncthreads();

    const int em = tid >> 5;          // bond group: bonds em*8 .. em*8+7
    const int dn = (tid & 31) << 2;   // dim group: dims dn .. dn+3
    const float* AsB = &As[em * 8 * 148];

    float aK[8][4], aV[8][4], aQ[8][4], aE[8][4];
    #pragma unroll
    for (int m = 0; m < 8; ++m)
        #pragma unroll
        for (int j = 0; j < 4; ++j) { aK[m][j]=0.f; aV[m][j]=0.f; aQ[m][j]=0.f; aE[m][j]=0.f; }

    #pragma unroll 2
    for (int c = 0; c < 128; ++c) {
        float4 wk = *(const float4*)&Wk[c * OUT_DIM + dn];
        float4 wv = *(const float4*)&Wv[c * OUT_DIM + dn];
        float4 wq = *(const float4*)&Wq[c * OUT_DIM + dn];
        #pragma unroll
        for (int m = 0; m < 8; ++m) {
            float a = AsB[m * 148 + c];      // wave-broadcast LDS read
            aK[m][0] = fmaf(a, wk.x, aK[m][0]); aK[m][1] = fmaf(a, wk.y, aK[m][1]);
            aK[m][2] = fmaf(a, wk.z, aK[m][2]); aK[m][3] = fmaf(a, wk.w, aK[m][3]);
            aV[m][0] = fmaf(a, wv.x, aV[m][0]); aV[m][1] = fmaf(a, wv.y, aV[m][1]);
            aV[m][2] = fmaf(a, wv.z, aV[m][2]); aV[m][3] = fmaf(a, wv.w, aV[m][3]);
            aQ[m][0] = fmaf(a, wq.x, aQ[m][0]); aQ[m][1] = fmaf(a, wq.y, aQ[m][1]);
            aQ[m][2] = fmaf(a, wq.z, aQ[m][2]); aQ[m][3] = fmaf(a, wq.w, aQ[m][3]);
        }
    }
    #pragma unroll 2
    for (int g = 0; g < 20; ++g) {
        float4 wk = *(const float4*)&Wk[(INPUT_DIM + g) * OUT_DIM + dn];
        float4 wv = *(const float4*)&Wv[(INPUT_DIM + g) * OUT_DIM + dn];
        float4 w0 = *(const float4*)&We0[g * OUT_DIM + dn];
        #pragma unroll
        for (int m = 0; m < 8; ++m) {
            float a = AsB[m * 148 + 128 + g];
            aK[m][0] = fmaf(a, wk.x, aK[m][0]); aK[m][1] = fmaf(a, wk.y, aK[m][1]);
            aK[m][2] = fmaf(a, wk.z, aK[m][2]); aK[m][3] = fmaf(a, wk.w, aK[m][3]);
            aV[m][0] = fmaf(a, wv.x, aV[m][0]); aV[m][1] = fmaf(a, wv.y, aV[m][1]);
            aV[m][2] = fmaf(a, wv.z, aV[m][2]); aV[m][3] = fmaf(a, wv.w, aV[m][3]);
            aE[m][0] = fmaf(a, w0.x, aE[m][0]); aE[m][1] = fmaf(a, w0.y, aE[m][1]);
            aE[m][2] = fmaf(a, w0.z, aE[m][2]); aE[m][3] = fmaf(a, w0.w, aE[m][3]);
        }
    }

    #pragma unroll
    for (int m = 0; m < 8; ++m) {
        int e = e0 + em * 8 + m;
        if (e < E) {
            *(float4*)&KB[(size_t)e * OUT_DIM + dn] =
                make_float4(aK[m][0], aK[m][1], aK[m][2], aK[m][3]);
            *(float4*)&VB[(size_t)e * OUT_DIM + dn] =
                make_float4(aV[m][0], aV[m][1], aV[m][2], aV[m][3]);
            *(float4*)&QE[(size_t)e * OUT_DIM + dn] =
                make_float4(aQ[m][0] * tanhf(aE[m][0]), aQ[m][1] * tanhf(aE[m][1]),
                            aQ[m][2] * tanhf(aE[m][2]), aQ[m][3] * tanhf(aE[m][3]));
        }
    }
}

// r-only projections (K=20): EA1 = tanh(r@We1), ERV = EA1*(r@Wv[148:168]),
// QRK2[e][h] = dot_h(QE, r@Wk[148:168]). Two sequential low-pressure passes.
__global__ __launch_bounds__(256) void redge_kernel(
    const float* __restrict__ r_feat,
    const float* __restrict__ QE,
    const float* __restrict__ Wk,
    const float* __restrict__ Wv,
    const float* __restrict__ We1,
    float* __restrict__ EA1,
    float* __restrict__ ERV,
    float* __restrict__ QRK2,
    int E)
{
    __shared__ float Rs[BM][NUM_GAUSS];
    const int tid = threadIdx.x;
    const int e0 = blockIdx.x * BM;

    for (int i = tid; i < BM * 5; i += 256) {
        int e = i / 5, q = (i % 5) << 2;
        float4 v = make_float4(0.f, 0.f, 0.f, 0.f);
        if (e0 + e < E) v = *(const float4*)&r_feat[(size_t)(e0 + e) * NUM_GAUSS + q];
        Rs[e][q] = v.x; Rs[e][q+1] = v.y; Rs[e][q+2] = v.z; Rs[e][q+3] = v.w;
    }
    __syncthreads();

    const int em = tid >> 5;
    const int dn = (tid & 31) << 2;

    // ---- pass A: EA1, ERV ----
    {
        float a1[8][4], aS[8][4];
        #pragma unroll
        for (int m = 0; m < 8; ++m)
            #pragma unroll
            for (int j = 0; j < 4; ++j) { a1[m][j] = 0.f; aS[m][j] = 0.f; }

        #pragma unroll 2
        for (int g = 0; g < 20; ++g) {
            float4 w1 = *(const float4*)&We1[g * OUT_DIM + dn];
            float4 wv = *(const float4*)&Wv[(148 + g) * OUT_DIM + dn];
            #pragma unroll
            for (int m = 0; m < 8; ++m) {
                float a = Rs[em * 8 + m][g];
                a1[m][0] = fmaf(a, w1.x, a1[m][0]); a1[m][1] = fmaf(a, w1.y, a1[m][1]);
                a1[m][2] = fmaf(a, w1.z, a1[m][2]); a1[m][3] = fmaf(a, w1.w, a1[m][3]);
                aS[m][0] = fmaf(a, wv.x, aS[m][0]); aS[m][1] = fmaf(a, wv.y, aS[m][1]);
                aS[m][2] = fmaf(a, wv.z, aS[m][2]); aS[m][3] = fmaf(a, wv.w, aS[m][3]);
            }
        }
        #pragma unroll
        for (int m = 0; m < 8; ++m) {
            int e = e0 + em * 8 + m;
            if (e < E) {
                float t0 = tanhf(a1[m][0]), t1 = tanhf(a1[m][1]);
                float t2 = tanhf(a1[m][2]), t3 = tanhf(a1[m][3]);
                *(float4*)&EA1[(size_t)e * OUT_DIM + dn] = make_float4(t0, t1, t2, t3);
                *(float4*)&ERV[(size_t)e * OUT_DIM + dn] =
                    make_float4(t0 * aS[m][0], t1 * aS[m][1], t2 * aS[m][2], t3 * aS[m][3]);
            }
        }
    }

    // ---- pass B: RK2 (regs) -> QRK2 per-head dot with QE ----
    {
        float aR[8][4];
        #pragma unroll
        for (int m = 0; m < 8; ++m)
            #pragma unroll
            for (int j = 0; j < 4; ++j) aR[m][j] = 0.f;

        #pragma unroll 2
        for (int g = 0; g < 20; ++g) {
            float4 wk = *(const float4*)&Wk[(148 + g) * OUT_DIM + dn];
            #pragma unroll
            for (int m = 0; m < 8; ++m) {
                float a = Rs[em * 8 + m][g];
                aR[m][0] = fmaf(a, wk.x, aR[m][0]); aR[m][1] = fmaf(a, wk.y, aR[m][1]);
                aR[m][2] = fmaf(a, wk.z, aR[m][2]); aR[m][3] = fmaf(a, wk.w, aR[m][3]);
            }
        }
        const int hh = (tid & 31) >> 1;   // head owning dims dn..dn+3 (with partner lane)
        #pragma unroll
        for (int m = 0; m < 8; ++m) {
            int e = e0 + em * 8 + m;
            float s = 0.f;
            if (e < E) {
                float4 q = *(const float4*)&QE[(size_t)e * OUT_DIM + dn];  // L2-warm
                s = q.x*aR[m][0] + q.y*aR[m][1] + q.z*aR[m][2] + q.w*aR[m][3];
            }
            s += __shfl_xor(s, 1);
            if ((tid & 1) == 0 && e < E) QRK2[(size_t)e * NH + hh] = s;
        }
    }
}

// One 64-lane wave per segment; lane l owns dims (2l, 2l+1); head h = l>>2.
__global__ __launch_bounds__(256, 2) void attn_wave_kernel(
    const float* __restrict__ pos,
    const int*   __restrict__ idx_i,
    const int*   __restrict__ idx_j,
    const int*   __restrict__ idx_k,
    const int*   __restrict__ idx_kj,
    const float* __restrict__ Wk,
    const float* __restrict__ Wv,
    const float* __restrict__ KB,
    const float* __restrict__ VB,
    const float* __restrict__ QE,
    const float* __restrict__ EA1,
    const float* __restrict__ ERV,
    const float* __restrict__ QRK2,
    float* __restrict__ out,
    int E)
{
    __shared__ float afL[WPB][12][13];
    __shared__ float alphaL[WPB][12][16];

    // bijective XCD-aware swizzle: contiguous block ranges per XCD (m204)
    unsigned bid = blockIdx.x, nwg = gridDim.x;
    unsigned qq = nwg >> 3, rr = nwg & 7, xc = bid & 7, rest = bid >> 3;
    unsigned swz = (xc < rr ? xc * (qq + 1) : rr * (qq + 1) + (xc - rr) * qq) + rest;

    const int l = threadIdx.x & 63;
    const int wvn = __builtin_amdgcn_readfirstlane(threadIdx.x >> 6);
    const int e = (int)swz * WPB + wvn;
    if (e >= E) return;                 // wave-uniform
    const int h = l >> 2;
    const int a = l & 3;

    // segment-constant geometry (uniform loads)
    const int ii = idx_i[(size_t)e * 12];
    const int jj = idx_j[(size_t)e * 12];
    const float pix = pos[ii*3+0], piy = pos[ii*3+1], piz = pos[ii*3+2];
    const float jx = pos[jj*3+0]-pix, jy = pos[jj*3+1]-piy, jz = pos[jj*3+2]-piz;

    // per-lane triplet geometry + angular features -> LDS
    int kj = 0;
    if (l < 12) {
        int t = 12 * e + l;
        kj = idx_kj[t];
        int kk = idx_k[t];
        float kx = pos[kk*3+0]-pix, ky = pos[kk*3+1]-piy, kz = pos[kk*3+2]-piz;
        float aa = jx*kx + jy*ky + jz*kz;
        float cx = jy*kz - jz*ky, cy = jz*kx - jx*kz, cz = jx*ky - jy*kx;
        float bb = sqrtf(cx*cx + cy*cy + cz*cz);
        float ang = atan2f(bb, aa);
        float af0[13];
        af0[0] = ang;
        const float fr[6] = {1.f, 2.f, 3.f, 1.f, 0.5f, 1.f/3.f};
        #pragma unroll
        for (int q = 0; q < 6; ++q)
            __sincosf(ang * fr[q], &af0[1+q], &af0[7+q]);
        #pragma unroll
        for (int c = 0; c < 13; ++c) afL[wvn][l][c] = af0[c];
    }

    const float2 qe  = *(const float2*)&QE [(size_t)e * OUT_DIM + 2*l];
    const float2 ea  = *(const float2*)&EA1[(size_t)e * OUT_DIM + 2*l];
    const float2 erv = *(const float2*)&ERV[(size_t)e * OUT_DIM + 2*l];
    const float qrk2 = QRK2[(size_t)e * NH + h];

    // qwk[c]: per-head projected query against angular key weights
    float qwk[13];
    #pragma unroll
    for (int c = 0; c < 13; ++c) {
        float2 w = *(const float2*)&Wk[(168 + c) * OUT_DIM + 2*l];
        float p = qe.x*w.x + qe.y*w.y;
        p += __shfl_xor(p, 1); p += __shfl_xor(p, 2);
        qwk[c] = p;
    }

    // QK logits (bond part); lane keeps t with t&3==a
    float qk3[3];
    #pragma unroll
    for (int t = 0; t < 12; ++t) {
        int kjt = __builtin_amdgcn_readlane(kj, t);
        float2 kb = *(const float2*)&KB[(size_t)kjt * OUT_DIM + 2*l];
        float v = qe.x*kb.x + qe.y*kb.y;
        v += __shfl_xor(v, 1); v += __shfl_xor(v, 2);
        if ((t & 3) == a) qk3[t >> 2] = v;
    }

    wave_lds_fence();   // af ready

    // angular part + combine
    float lg[3];
    #pragma unroll
    for (int q = 0; q < 3; ++q) {
        int t = a + 4*q;
        float s = 0.f;
        #pragma unroll
        for (int c = 0; c < 13; ++c) s = fmaf(afL[wvn][t][c], qwk[c], s);
        lg[q] = (qk3[q] + s + qrk2) * SCALE;
    }

    // wave-parallel softmax over 12 (per head)
    float m = fmaxf(lg[0], fmaxf(lg[1], lg[2]));
    m = fmaxf(m, __shfl_xor(m, 1)); m = fmaxf(m, __shfl_xor(m, 2));
    float ex0 = __expf(lg[0]-m), ex1 = __expf(lg[1]-m), ex2 = __expf(lg[2]-m);
    float ss = ex0 + ex1 + ex2;
    ss += __shfl_xor(ss, 1); ss += __shfl_xor(ss, 2);
    float inv = 1.f / (ss + 1e-16f);
    float al0 = ex0*inv, al1 = ex1*inv, al2 = ex2*inv;
    float Sh = ss * inv;

    alphaL[wvn][a    ][h] = al0;
    alphaL[wvn][a + 4][h] = al1;
    alphaL[wvn][a + 8][h] = al2;

    // waf[c] = sum_t alpha[t]*af[t][c] (partial over own 3 t, then 4-lane reduce)
    float waf[13];
    #pragma unroll
    for (int c = 0; c < 13; ++c) {
        float wp = al0*afL[wvn][a][c] + al1*afL[wvn][a+4][c] + al2*afL[wvn][a+8][c];
        wp += __shfl_xor(wp, 1); wp += __shfl_xor(wp, 2);
        waf[c] = wp;
    }

    wave_lds_fence();   // alpha ready

    // value accumulation
    float accx = 0.f, accy = 0.f;
    #pragma unroll
    for (int t = 0; t < 12; ++t) {
        int kjt = __builtin_amdgcn_readlane(kj, t);
        float2 vb = *(const float2*)&VB[(size_t)kjt * OUT_DIM + 2*l];
        float alt = alphaL[wvn][t][h];
        accx = fmaf(alt, vb.x, accx);
        accy = fmaf(alt, vb.y, accy);
    }
    float vAx = 0.f, vAy = 0.f;
    #pragma unroll
    for (int c = 0; c < 13; ++c) {
        float2 w = *(const float2*)&Wv[(168 + c) * OUT_DIM + 2*l];
        vAx = fmaf(waf[c], w.x, vAx);
        vAy = fmaf(waf[c], w.y, vAy);
    }
    float2 o;
    o.x = ea.x * (accx + vAx) + erv.x * Sh;
    o.y = ea.y * (accy + vAy) + erv.y * Sh;
    *(float2*)&out[(size_t)e * OUT_DIM + 2*l] = o;
}

// ---------------- generic fallback (unused when T == E*12) ----------------
__global__ __launch_bounds__(128) void attn_generic_kernel(
    const float* __restrict__ pos,
    const int*   __restrict__ idx_i,
    const int*   __restrict__ idx_j,
    const int*   __restrict__ idx_k,
    const int*   __restrict__ idx_kj,
    const int*   __restrict__ idx_ji,
    const float* __restrict__ Wk,
    const float* __restrict__ Wv,
    const float* __restrict__ We1,
    const float* __restrict__ r_feat,
    const float* __restrict__ KB,
    const float* __restrict__ VB,
    const float* __restrict__ QE,
    float* __restrict__ out,
    int E, int T)
{
    __shared__ float rs[NUM_GAUSS];
    __shared__ float af[MAXT][13];
    __shared__ float logit[MAXT][NH];
    __shared__ float qwk[NH][13];
    __shared__ float waf[NH][13];
    __shared__ int   kjs[MAXT];
    __shared__ float qrk2s[NH];
    __shared__ float Shs[NH];

    const int e = blockIdx.x;
    const int d = threadIdx.x;
    const int h8 = d >> 3;

    int l = 0, hi = T;
    while (l < hi) { int mid = (l + hi) >> 1; if (idx_ji[mid] < e) l = mid + 1; else hi = mid; }
    int lo = l, c2 = 0;
    while (lo + c2 < T && c2 < MAXT && idx_ji[lo + c2] == e) ++c2;
    int cnt = c2;

    if (d < NUM_GAUSS) rs[d] = r_feat[(size_t)e * NUM_GAUSS + d];
    if (d < cnt) {
        int t = lo + d;
        kjs[d] = idx_kj[t];
        int ii = idx_i[t], jj = idx_j[t], kk = idx_k[t];
        float pix = pos[ii*3+0], piy = pos[ii*3+1], piz = pos[ii*3+2];
        float jx = pos[jj*3+0]-pix, jy = pos[jj*3+1]-piy, jz = pos[jj*3+2]-piz;
        float kx = pos[kk*3+0]-pix, ky = pos[kk*3+1]-piy, kz = pos[kk*3+2]-piz;
        float aa = jx*kx + jy*ky + jz*kz;
        float cx = jy*kz - jz*ky, cy = jz*kx - jx*kz, cz = jx*ky - jy*kx;
        float bb = sqrtf(cx*cx + cy*cy + cz*cz);
        float ang = atan2f(bb, aa);
        af[d][0] = ang;
        const float fr[6] = {1.f, 2.f, 3.f, 1.f, 0.5f, 1.f/3.f};
        #pragma unroll
        for (int q = 0; q < 6; ++q) {
            float s, cc;
            __sincosf(ang * fr[q], &s, &cc);
            af[d][1 + q] = s;
            af[d][7 + q] = cc;
        }
    }
    __syncthreads();

    const float qe = QE[(size_t)e * OUT_DIM + d];
    float s1 = 0.f, sk = 0.f, sv = 0.f;
    #pragma unroll
    for (int g = 0; g < NUM_GAUSS; ++g) {
        float rg = rs[g];
        s1 = fmaf(rg, We1[g * OUT_DIM + d], s1);
        sk = fmaf(rg, Wk[(148 + g) * OUT_DIM + d], sk);
        sv = fmaf(rg, Wv[(148 + g) * OUT_DIM + d], sv);
    }
    const float ea1 = tanhf(s1);
    const float rv2 = sv;

    {
        float v = qe * sk;
        v += __shfl_xor(v, 1, 8); v += __shfl_xor(v, 2, 8); v += __shfl_xor(v, 4, 8);
        if ((d & 7) == 0) qrk2s[h8] = v;
    }
    {
        float p[13];
        #pragma unroll
        for (int c = 0; c < 13; ++c) p[c] = qe * Wk[(168 + c) * OUT_DIM + d];
        #pragma unroll
        for (int c = 0; c < 13; ++c) {
            float v = p[c];
            v += __shfl_xor(v, 1, 8); v += __shfl_xor(v, 2, 8); v += __shfl_xor(v, 4, 8);
            if ((d & 7) == 0) qwk[h8][c] = v;
        }
    }
    for (int t = 0; t < cnt; ++t) {
        float lv = qe * KB[(size_t)kjs[t] * OUT_DIM + d];
        lv += __shfl_xor(lv, 1, 8); lv += __shfl_xor(lv, 2, 8); lv += __shfl_xor(lv, 4, 8);
        if ((d & 7) == 0) logit[t][h8] = lv;
    }
    __syncthreads();
    {
        const int hh = d & 15;
        for (int t = d >> 4; t < cnt; t += 8) {
            float s = 0.f;
            #pragma unroll
            for (int c = 0; c < 13; ++c) s = fmaf(af[t][c], qwk[hh][c], s);
            logit[t][hh] = (logit[t][hh] + s + qrk2s[hh]) * SCALE;
        }
    }
    __syncthreads();
    if (d < NH) {
        float m = -1e30f;
        for (int t = 0; t < cnt; ++t) m = fmaxf(m, logit[t][d]);
        float s = 0.f;
        for (int t = 0; t < cnt; ++t) { float ex = __expf(logit[t][d] - m); logit[t][d] = ex; s += ex; }
        float inv = 1.f / (s + 1e-16f);
        for (int t = 0; t < cnt; ++t) logit[t][d] *= inv;
        Shs[d] = s * inv;
    }
    __syncthreads();
    {
        const int hh = d & 15;
        int c = d >> 4;
        float w1 = 0.f;
        for (int t = 0; t < cnt; ++t) w1 = fmaf(logit[t][hh], af[t][c], w1);
        waf[hh][c] = w1;
        c += 8;
        if (c < 13) {
            float w2 = 0.f;
            for (int t = 0; t < cnt; ++t) w2 = fmaf(logit[t][hh], af[t][c], w2);
            waf[hh][c] = w2;
        }
    }
    __syncthreads();
    float vA = 0.f;
    #pragma unroll
    for (int c = 0; c < 13; ++c) vA = fmaf(waf[h8][c], Wv[(168 + c) * OUT_DIM + d], vA);
    float acc = 0.f;
    for (int t = 0; t < cnt; ++t)
        acc = fmaf(logit[t][h8], VB[(size_t)kjs[t] * OUT_DIM + d], acc);
    out[(size_t)e * OUT_DIM + d] = ea1 * (acc + vA + rv2 * Shs[h8]);
}

extern "C" void kernel_launch(void* const* d_in, const int* in_sizes, int n_in,
                              void* d_out, int out_size, void* d_ws, size_t ws_size,
                              hipStream_t stream) {
    const float* h_bond = (const float*)d_in[1];
    const float* pos    = (const float*)d_in[2];
    const int*   bidx   = (const int*)d_in[3];
    const int*   idx_i  = (const int*)d_in[4];
    const int*   idx_j  = (const int*)d_in[5];
    const int*   idx_k  = (const int*)d_in[6];
    const int*   idx_kj = (const int*)d_in[7];
    const int*   idx_ji = (const int*)d_in[8];
    const float* Wk     = (const float*)d_in[9];
    const float* Wv     = (const float*)d_in[10];
    const float* Wq     = (const float*)d_in[11];
    const float* We0    = (const float*)d_in[12];
    const float* We1    = (const float*)d_in[13];

    const int E = in_sizes[1] / INPUT_DIM;
    const int T = in_sizes[4];

    float* ws = (float*)d_ws;
    float* r_feat = ws;                               // E*20
    float* KB   = r_feat + (size_t)E * NUM_GAUSS;     // E*128
    float* VB   = KB   + (size_t)E * OUT_DIM;         // E*128
    float* QE   = VB   + (size_t)E * OUT_DIM;         // E*128
    float* EA1  = QE   + (size_t)E * OUT_DIM;         // E*128
    float* ERV  = EA1  + (size_t)E * OUT_DIM;         // E*128
    float* QRK2 = ERV  + (size_t)E * OUT_DIM;         // E*16
    // total: E*(20 + 5*128 + 16)*4 B  (~133 MB for E=49152)

    rbf_kernel<<<(E + 255) / 256, 256, 0, stream>>>(pos, bidx, r_feat, E);

    bond_proj_kernel<<<(E + BM - 1) / BM, 256, 0, stream>>>(
        h_bond, r_feat, Wk, Wv, Wq, We0, KB, VB, QE, E);

    redge_kernel<<<(E + BM - 1) / BM, 256, 0, stream>>>(
        r_feat, QE, Wk, Wv, We1, EA1, ERV, QRK2, E);

    if (T == E * 12) {
        attn_wave_kernel<<<(E + WPB - 1) / WPB, 64 * WPB, 0, stream>>>(
            pos, idx_i, idx_j, idx_k, idx_kj,
            Wk, Wv, KB, VB, QE, EA1, ERV, QRK2, (float*)d_out, E);
    } else {
        attn_generic_kernel<<<E, 128, 0, stream>>>(
            pos, idx_i, idx_j, idx_k, idx_kj, idx_ji,
            Wk, Wv, We1, r_feat, KB, VB, QE, (float*)d_out, E, T);
    }
}